// Round 4
// baseline (72.200 us; speedup 1.0000x reference)
//
#include <hip/hip_runtime.h>
#include <hip/hip_bf16.h>

#define P_ADC 64
#define M_SEN 256
#define B_BLK 32
#define BATCHN 4096

// Derived GEMM: Out[R=131072][128] = X[R][512] * W[512][128], W[k][p] = A[p][k]
#define GK 512
#define GN 128
#define GR (BATCHN * B_BLK)   // 131072 rows

typedef float  f32x4  __attribute__((ext_vector_type(4)));
typedef __bf16 bf16x8 __attribute__((ext_vector_type(8)));

// ---------------------------------------------------------------------------
// Kernel 1: build W in MFMA fragment order with a CUSTOM k-slot permutation.
// MFMA contraction is invariant to any bijective k-slot remap applied to both
// operands; we pick the remap that makes the GEMM's X loads cover full 64B
// lines per instruction:
//   wfrag[t][f][lane][j] holds W[k][n],
//     n = f*16 + (lane&15),  g = lane>>4,
//     k = t*32 + (j>>2)*16 + g*4 + (j&3)
// W[k][n] = A[n][k]:
//   A[p][m]: p<64,m<256 -> cos ; p<64,m>=256 -> -sin ; p>=64,m<256 -> sin ;
//            p>=64,m>=256 -> cos   (ang = -pv[p&63] * (m&255) * 2pi/256)
// ---------------------------------------------------------------------------
__global__ void build_w_frags(const float* __restrict__ pv, __bf16* __restrict__ wfrag) {
    int tid = blockIdx.x * blockDim.x + threadIdx.x;
    if (tid >= 16 * 8 * 64) return;
    int lane = tid & 63;
    int f    = (tid >> 6) & 7;
    int t    = tid >> 9;
    int n    = f * 16 + (lane & 15);
    int g    = lane >> 4;
    int q    = n & 63;
    bool ph  = (n >= 64);
    float pq = pv[q];
    const float step = -0.02454369260617025967f; // -2*pi/256
    bf16x8 v;
#pragma unroll
    for (int j = 0; j < 8; ++j) {
        int k  = t * 32 + ((j >> 2) << 4) + g * 4 + (j & 3);
        int mm = k & 255;
        bool mh = (k >= 256);
        float ang = pq * (float)mm * step;
        float s, c;
        sincosf(ang, &s, &c);
        float a = (ph == mh) ? c : (ph ? s : -s);
        v[j] = (__bf16)a;
    }
    *(bf16x8*)(wfrag + (size_t)tid * 8) = v;
}

// ---------------------------------------------------------------------------
// Kernel 2: persistent blocks. Grid=256 (1/CU), 1024 thr = 16 waves.
// W staged in LDS ONCE (128 KB); block then processes 2 stripes of 256 rows
// (wave = 16 rows x 128 cols per stripe). Stripe-0 stores overlap stripe-1
// loads. Swapped operands: A=W (from LDS), B=X, D reg r = out col -> f32x4
// stores. X loads cover full 64B lines per instruction (see k-permutation).
// ---------------------------------------------------------------------------
__global__ __launch_bounds__(1024) void analog_gemm(const float* __restrict__ X,
                                                    const __bf16* __restrict__ W,
                                                    float* __restrict__ out) {
    __shared__ __bf16 lw[16 * 8 * 64 * 8];   // 65536 bf16 = 128 KB

    const int tid = threadIdx.x;

    // Stage W global->LDS once: 8192 x 16B chunks, 1024 threads x 8 each.
    {
        const f32x4* src = (const f32x4*)W;
        f32x4* dst = (f32x4*)lw;
#pragma unroll
        for (int i = 0; i < 8; ++i)
            dst[i * 1024 + tid] = src[i * 1024 + tid];
    }
    __syncthreads();

    const int lane = tid & 63;
    const int wave = tid >> 6;
    const int lr = lane & 15;          // X row within 16-row stripe (B-frag 16-dim)
    const int g  = lane >> 4;          // k sub-group

    const bf16x8* wp = (const bf16x8*)lw + lane;   // + (t*8+f)*64

#pragma unroll
    for (int s = 0; s < 2; ++s) {
        const long rowbase = (long)blockIdx.x * 512 + (long)s * 256 + (long)wave * 16;
        const float* xp = X + (rowbase + lr) * (long)GK + g * 4;

        f32x4 acc[8];
#pragma unroll
        for (int f = 0; f < 8; ++f) acc[f] = (f32x4)0.0f;

#pragma unroll
        for (int t = 0; t < 16; ++t) {
            f32x4 xa = *(const f32x4*)(xp + t * 32);        // k = t*32 + g*4 + [0,4)
            f32x4 xb = *(const f32x4*)(xp + t * 32 + 16);   // k = t*32 + 16 + g*4 + [0,4)

            bf16x8 b;
#pragma unroll
            for (int j = 0; j < 4; ++j) {
                b[j]     = (__bf16)xa[j];
                b[4 + j] = (__bf16)xb[j];
            }

#pragma unroll
            for (int f = 0; f < 8; ++f) {
                bf16x8 w = wp[(t * 8 + f) * 64];
                acc[f] = __builtin_amdgcn_mfma_f32_16x16x32_bf16(w, b, acc[f], 0, 0, 0);
            }
        }

        // lane stores row rowbase+lr, cols f*16 + g*4 .. +3
        float* op = out + (rowbase + lr) * (long)GN + g * 4;
#pragma unroll
        for (int f = 0; f < 8; ++f)
            __builtin_nontemporal_store(acc[f], (f32x4*)(op + f * 16));
    }
}

extern "C" void kernel_launch(void* const* d_in, const int* in_sizes, int n_in,
                              void* d_out, int out_size, void* d_ws, size_t ws_size,
                              hipStream_t stream) {
    const float* x  = (const float*)d_in[0];
    const float* pv = (const float*)d_in[1];
    float* out      = (float*)d_out;
    __bf16* wfrag   = (__bf16*)d_ws;   // 16*8*64*8*2 = 131072 bytes

    hipLaunchKernelGGL(build_w_frags, dim3(32), dim3(256), 0, stream, pv, wfrag);
    hipLaunchKernelGGL(analog_gemm, dim3(256), dim3(1024), 0, stream, x, wfrag, out);
}